// Round 9
// baseline (269.955 us; speedup 1.0000x reference)
//
#include <hip/hip_runtime.h>

typedef __attribute__((ext_vector_type(4)))  float          f32x4;
typedef __attribute__((ext_vector_type(2)))  float          f32x2;
typedef __attribute__((ext_vector_type(16))) float          f32x16;
typedef __attribute__((ext_vector_type(8)))  short          s16x8;
typedef __attribute__((ext_vector_type(4)))  unsigned short u16x4;
typedef __attribute__((ext_vector_type(8)))  unsigned short u16x8;

#define MFMA_BF16(a, b, c) __builtin_amdgcn_mfma_f32_16x16x32_bf16((a), (b), (c), 0, 0, 0)
#define MFMA32(a, b, c)    __builtin_amdgcn_mfma_f32_32x32x16_bf16((a), (b), (c), 0, 0, 0)

static constexpr int Bb = 2, Ss = 2048, Ee = 1024, Hh = 16, Dd = 64;
static constexpr size_t M4 = 4u * 1024 * 1024;
static constexpr size_t M1 = 1024 * 1024;

__device__ __forceinline__ unsigned short f2b(float f) {
    unsigned u = __builtin_bit_cast(unsigned, f);
    u += 0x7fffu + ((u >> 16) & 1u);
    return (unsigned short)(u >> 16);
}

__device__ __forceinline__ void gld_lds16(const unsigned short* g, unsigned short* l) {
    __builtin_amdgcn_global_load_lds(
        (const __attribute__((address_space(1))) unsigned int*)g,
        (__attribute__((address_space(3))) unsigned int*)l, 16, 0, 0);
}

// ---------------------------------------------------------------------------
// Convert fp32 inputs to bf16 workspace (one f32x4 -> u16x4 per thread,
// pure stride-16 coalesced reads) + mask -> float array.
// ---------------------------------------------------------------------------
struct CvtArgs { const float* src[7]; unsigned short* dst;
                 const int* mask; float* maskf; };

__global__ __launch_bounds__(256) void cvt_bf16(CvtArgs a)
{
    if (blockIdx.x == 16384) { // mask -> float (4096 elems)
#pragma unroll
        for (int j = 0; j < 16; j++) {
            int idx = threadIdx.x + j * 256;
            a.maskf[idx] = a.mask[idx] ? 1.f : 0.f;
        }
        return;
    }
    size_t i = ((size_t)blockIdx.x * 256 + threadIdx.x) * 4;
    int seg; size_t off;
    if (i < 3 * M4) { seg = (int)(i / M4);     off = i % M4; }
    else            { size_t j = i - 3 * M4;
                      seg = 3 + (int)(j / M1); off = j % M1; }
    f32x4 x = *(const f32x4*)(a.src[seg] + off);
    *(u16x4*)(a.dst + i) = (u16x4){f2b(x[0]), f2b(x[1]), f2b(x[2]), f2b(x[3])};
}

// ---------------------------------------------------------------------------
// bf16 GEMM body, 128x128 tile, BK=32 (frozen R8 structure).
// OUT_MODE: 0 fp32-out stored as f32; 1 bf16 [m][n]; 2 bf16 V-transposed;
// 3 bf16 scaled by 0.125*log2(e) (Q path).
// ---------------------------------------------------------------------------
template <int OUT_MODE>
__device__ __forceinline__ void gemm_bf16_body(const unsigned short* __restrict__ A,
                                               const unsigned short* __restrict__ W,
                                               const float* __restrict__ bias,
                                               void* __restrict__ Cv,
                                               int m0, int n0)
{
    __shared__ __align__(16) unsigned short Al[128 * 32];
    __shared__ __align__(16) unsigned short Bl[128 * 32];

    const int tid  = threadIdx.x;
    const int lane = tid & 63;
    const int wid  = tid >> 6;
    const int quad = lane >> 4;
    const int lr   = lane & 15;
    const int wr   = (wid >> 1) * 64;
    const int wc   = (wid & 1) * 64;

    const int srow = wid * 32 + (lane >> 2);
    const int sk8  = (lane & 3) * 8;
    const unsigned short* gA = A + (size_t)(m0 + srow) * 1024 + sk8;
    const unsigned short* gW = W + (size_t)(n0 + srow) * 1024 + sk8;
    unsigned short* lA = &Al[wid * 1024];
    unsigned short* lW = &Bl[wid * 1024];

    f32x4 acc[4][4];
#pragma unroll
    for (int i = 0; i < 4; i++)
#pragma unroll
        for (int j = 0; j < 4; j++) acc[i][j] = (f32x4){0.f, 0.f, 0.f, 0.f};

    for (int ks = 0; ks < 1024; ks += 32) {
        __syncthreads();
        gld_lds16(gA + ks,              lA);
        gld_lds16(gA + ks + 16 * 1024,  lA + 512);
        gld_lds16(gW + ks,              lW);
        gld_lds16(gW + ks + 16 * 1024,  lW + 512);
        __syncthreads();

        s16x8 af[4], bf[4];
#pragma unroll
        for (int t = 0; t < 4; t++) {
            af[t] = *(const s16x8*)&Al[(wr + t * 16 + lr) * 32 + quad * 8];
            bf[t] = *(const s16x8*)&Bl[(wc + t * 16 + lr) * 32 + quad * 8];
        }
#pragma unroll
        for (int mt = 0; mt < 4; mt++)
#pragma unroll
            for (int nt = 0; nt < 4; nt++)
                acc[mt][nt] = MFMA_BF16(af[mt], bf[nt], acc[mt][nt]);
    }

#pragma unroll
    for (int mt = 0; mt < 4; mt++)
#pragma unroll
        for (int nt = 0; nt < 4; nt++) {
            int   col  = n0 + wc + nt * 16 + lr;
            float bcol = bias[col];
            int   rbase = m0 + wr + mt * 16 + quad * 4;
            if (OUT_MODE == 2) {
                int bb = rbase >> 11, s = rbase & 2047;
                u16x4 pk;
#pragma unroll
                for (int r = 0; r < 4; r++) pk[r] = f2b(acc[mt][nt][r] + bcol);
                *(u16x4*)&((unsigned short*)Cv)[((size_t)(bb * 1024 + col)) * 2048 + s] = pk;
            } else if (OUT_MODE == 0) {
#pragma unroll
                for (int r = 0; r < 4; r++)
                    ((float*)Cv)[(size_t)(rbase + r) * 1024 + col] = acc[mt][nt][r] + bcol;
            } else {
#pragma unroll
                for (int r = 0; r < 4; r++) {
                    float v = acc[mt][nt][r] + bcol;
                    if (OUT_MODE == 3) v *= 0.180336884f; // 0.125 * log2(e)
                    ((unsigned short*)Cv)[(size_t)(rbase + r) * 1024 + col] = f2b(v);
                }
            }
        }
}

struct GArgs {
    const unsigned short* A[3];
    const unsigned short* W[3];
    const float* bias[3];
    unsigned short* C[3];
};

__global__ __launch_bounds__(256) void proj_gemm(GArgs ga)
{
    const int id  = blockIdx.x;
    const int xcd = id & 7;
    const int t   = id >> 3;        // 0..95
    const int z   = t >> 5;
    const int tt  = t & 31;
    const int n0  = (tt & 7) * 128;
    const int m0  = (xcd * 4 + (tt >> 3)) * 128;

    if (z == 2)      gemm_bf16_body<2>(ga.A[2], ga.W[2], ga.bias[2], ga.C[2], m0, n0);
    else if (z == 1) gemm_bf16_body<1>(ga.A[1], ga.W[1], ga.bias[1], ga.C[1], m0, n0);
    else             gemm_bf16_body<3>(ga.A[0], ga.W[0], ga.bias[0], ga.C[0], m0, n0);
}

__global__ __launch_bounds__(256)
void out_gemm(const unsigned short* __restrict__ A,
              const unsigned short* __restrict__ W,
              const float* __restrict__ bias,
              float* __restrict__ C)
{
    __shared__ __align__(16) unsigned short Al[128 * 32];
    __shared__ __align__(16) unsigned short Bl[64 * 32];

    const int id  = blockIdx.x;
    const int xcd = id & 7;
    const int t   = id >> 3;            // 0..63
    const int n0  = (t & 15) * 64;
    const int m0  = (xcd * 4 + (t >> 4)) * 128;

    const int tid  = threadIdx.x;
    const int lane = tid & 63;
    const int wid  = tid >> 6;
    const int quad = lane >> 4;
    const int lr   = lane & 15;
    const int wr   = (wid >> 1) * 64;
    const int wc   = (wid & 1) * 32;

    const int srowA = wid * 32 + (lane >> 2);
    const int srowW = wid * 16 + (lane >> 2);
    const int sk8   = (lane & 3) * 8;
    const unsigned short* gA = A + (size_t)(m0 + srowA) * 1024 + sk8;
    const unsigned short* gW = W + (size_t)(n0 + srowW) * 1024 + sk8;
    unsigned short* lA = &Al[wid * 1024];
    unsigned short* lW = &Bl[wid * 512];

    f32x4 acc[4][2];
#pragma unroll
    for (int i = 0; i < 4; i++)
#pragma unroll
        for (int j = 0; j < 2; j++) acc[i][j] = (f32x4){0.f, 0.f, 0.f, 0.f};

    for (int ks = 0; ks < 1024; ks += 32) {
        __syncthreads();
        gld_lds16(gA + ks,              lA);
        gld_lds16(gA + ks + 16 * 1024,  lA + 512);
        gld_lds16(gW + ks,              lW);
        __syncthreads();

        s16x8 af[4], bf[2];
#pragma unroll
        for (int mt = 0; mt < 4; mt++)
            af[mt] = *(const s16x8*)&Al[(wr + mt * 16 + lr) * 32 + quad * 8];
#pragma unroll
        for (int nt = 0; nt < 2; nt++)
            bf[nt] = *(const s16x8*)&Bl[(wc + nt * 16 + lr) * 32 + quad * 8];
#pragma unroll
        for (int mt = 0; mt < 4; mt++)
#pragma unroll
            for (int nt = 0; nt < 2; nt++)
                acc[mt][nt] = MFMA_BF16(af[mt], bf[nt], acc[mt][nt]);
    }

#pragma unroll
    for (int mt = 0; mt < 4; mt++)
#pragma unroll
        for (int nt = 0; nt < 2; nt++) {
            int   col  = n0 + wc + nt * 16 + lr;
            float bcol = bias[col];
            int   rbase = m0 + wr + mt * 16 + quad * 4;
#pragma unroll
            for (int r = 0; r < 4; r++)
                C[(size_t)(rbase + r) * 1024 + col] = acc[mt][nt][r] + bcol;
        }
}

// ---------------------------------------------------------------------------
// Flash attention v9: key-split PV accumulation + DMA staging.
// Block = (b, h, 64 q), 4 waves; wave (qh = wid&1, kh = wid>>1) owns the
// quarter [keys kh-half] x [q qh-half] for S^T AND keeps its own partial
// O (full d) over its key-half -> P is entirely wave-local, no cross-wave
// barrier: 2 barriers/tile (staging only). Partner waves (wid, wid+2)
// combine O + row-sums once at the end through LDS (stride-34 floats,
// conflict-free). K/V staged via global_load_lds into 32-col sub-arrays
// (satisfies lane*16-contiguous DMA dest, keeps 2-way-free frag reads).
// ---------------------------------------------------------------------------
__global__ __launch_bounds__(256)
void flash_attn(const unsigned short* __restrict__ Q,
                const unsigned short* __restrict__ K,
                const unsigned short* __restrict__ Vt,
                const float* __restrict__ maskf,
                unsigned short* __restrict__ O)
{
    constexpr int   PST = 36;               // P row stride (72 B, 2-way banks)
    constexpr float EPS = 9.31322575e-10f;  // 2^-30
    // KVl[0]=K d0-31, [1]=K d32-63, [2]=V keys kh=0, [3]=V keys kh=1
    __shared__ __align__(16) unsigned short KVl[4][64 * 32];
    __shared__ __align__(16) unsigned short Pl[4 * 32 * PST];
    __shared__ float lsqf[64];

    const int id    = blockIdx.x;
    const int xcd   = id & 7;
    const int local = id >> 3;
    const int pair  = xcd * 4 + (local >> 5);
    const int b     = pair >> 4;
    const int h     = pair & 15;
    const int q0    = (local & 31) * 64;

    const int tid  = threadIdx.x;
    const int lane = tid & 63;
    const int wid  = tid >> 6;
    const int l31  = lane & 31;
    const int hl   = lane >> 5;
    const int qh   = wid & 1;
    const int kh   = wid >> 1;

    // Q B-frags (n = q = qh*32+l31, k = d = db*16 + hl*8 + j)
    const unsigned short* qg =
        Q + (size_t)(b * 2048 + q0 + qh * 32 + l31) * 1024 + h * 64 + hl * 8;
    s16x8 qf[4];
#pragma unroll
    for (int db = 0; db < 4; db++) qf[db] = *(const s16x8*)(qg + db * 16);

    const float  mq  = maskf[b * 2048 + q0 + qh * 32 + l31];
    const float* mkp = maskf + b * 2048;

    // DMA staging: wave w stages 16-row group w (K keys / V d-rows).
    // lane l -> row w*16 + l/4, col (l&3)*8 (+32 for the second sub-array);
    // dest offset = l*16 B (contiguous) as the DMA requires.
    const unsigned short* gK =
        K + (size_t)(b * 2048 + wid * 16 + (lane >> 2)) * 1024 + h * 64 + (lane & 3) * 8;
    const unsigned short* gV =
        Vt + (size_t)(b * 1024 + h * 64 + wid * 16 + (lane >> 2)) * 2048 + (lane & 3) * 8;
    unsigned short* lK0 = &KVl[0][wid * 512];
    unsigned short* lK1 = &KVl[1][wid * 512];
    unsigned short* lV0 = &KVl[2][wid * 512];
    unsigned short* lV1 = &KVl[3][wid * 512];

    unsigned short* plw = &Pl[wid * 32 * PST];

    float  lsum    = 0.f;
    f32x16 accO[2];
    accO[0] = (f32x16){0.f,0.f,0.f,0.f,0.f,0.f,0.f,0.f,0.f,0.f,0.f,0.f,0.f,0.f,0.f,0.f};
    accO[1] = accO[0];

    for (int kt = 0; kt < 2048; kt += 64) {
        __syncthreads();
        const unsigned short* gKt = gK + (size_t)kt * 1024;
        const unsigned short* gVt = gV + kt;
        gld_lds16(gKt,      lK0);
        gld_lds16(gKt + 32, lK1);
        gld_lds16(gVt,      lV0);
        gld_lds16(gVt + 32, lV1);
        __syncthreads();

        // S^T quarter: D[m=key(kh-half)][n=q(qh-half)]
        f32x16 st = (f32x16){0.f,0.f,0.f,0.f,0.f,0.f,0.f,0.f,
                             0.f,0.f,0.f,0.f,0.f,0.f,0.f,0.f};
#pragma unroll
        for (int db = 0; db < 4; db++) {
            s16x8 kf = *(const s16x8*)&KVl[db >> 1]
                          [(kh * 32 + l31) * 32 + (db & 1) * 16 + hl * 8];
            st = MFMA32(kf, qf[db], st);
        }
        // exp2 + mask + pack into wave-local P[q][k-within-half]
#pragma unroll
        for (int rq = 0; rq < 4; rq++) {
            int   k4 = 4 * hl + 8 * rq; // key offset within the 32-key half
            f32x4 m4 = *(const f32x4*)&mkp[kt + kh * 32 + k4];
            unsigned u[4];
#pragma unroll
            for (int r = 0; r < 4; r++) {
                float e = __builtin_amdgcn_exp2f(st[rq * 4 + r]);
                float p = e * (m4[r] * mq) + EPS;
                lsum += p;
                u[r] = __builtin_bit_cast(unsigned, p) + 0x8000u;
            }
            uint2 w;
            w.x = __builtin_amdgcn_perm(u[1], u[0], 0x07060302u);
            w.y = __builtin_amdgcn_perm(u[3], u[2], 0x07060302u);
            *(uint2*)&plw[l31 * PST + k4] = w;
        }

        // PV partial: O[q(qh)][d 0..63] += P[q][kh-half] * V[kh-half][d]
#pragma unroll
        for (int kstep = 0; kstep < 2; kstep++) {
            s16x8 pf = *(const s16x8*)&plw[l31 * PST + kstep * 16 + hl * 8];
#pragma unroll
            for (int dt = 0; dt < 2; dt++) {
                s16x8 vf = *(const s16x8*)&KVl[2 + kh]
                              [(dt * 32 + l31) * 32 + kstep * 16 + hl * 8];
                accO[dt] = MFMA32(pf, vf, accO[dt]);
            }
        }
    }

    // combine partner waves (wid, wid+2): kh=1 dumps, kh=0 finalizes
    lsum += __shfl_xor(lsum, 32, 64); // hl halves of the key residues
    __syncthreads();
    if (kh == 1) {
        float* cb = (wid == 2) ? (float*)Pl : (float*)KVl;
        float* cl = cb + lane * 34;
#pragma unroll
        for (int dt = 0; dt < 2; dt++)
#pragma unroll
            for (int rg = 0; rg < 16; rg += 2)
                *(f32x2*)&cl[dt * 16 + rg] = (f32x2){accO[dt][rg], accO[dt][rg + 1]};
        cl[32] = lsum;
    }
    __syncthreads();
    if (kh == 0) {
        const float* cb = (wid == 0) ? (const float*)Pl : (const float*)KVl;
        const float* cl = cb + lane * 34;
        float ltot = lsum + cl[32];
        lsqf[qh * 32 + l31] = ltot; // wave-local write/read, no barrier needed
#pragma unroll
        for (int dt = 0; dt < 2; dt++)
#pragma unroll
            for (int rg = 0; rg < 16; rg += 2) {
                f32x2 pv = *(const f32x2*)&cl[dt * 16 + rg];
                accO[dt][rg]     += pv[0];
                accO[dt][rg + 1] += pv[1];
            }
        // epilogue: O C-layout col = d = dt*32+l31, row q = 4hl+8rq+r
#pragma unroll
        for (int rq = 0; rq < 4; rq++) {
            int   qr  = 4 * hl + 8 * rq;
            f32x4 ls4 = *(const f32x4*)&lsqf[qh * 32 + qr];
#pragma unroll
            for (int r = 0; r < 4; r++) {
                float rcp = __builtin_amdgcn_rcpf(ls4[r]);
                size_t orow = (size_t)(b * 2048 + q0 + qh * 32 + qr + r) * 1024 + h * 64;
#pragma unroll
                for (int dt = 0; dt < 2; dt++)
                    O[orow + dt * 32 + l31] = f2b(accO[dt][rq * 4 + r] * rcp);
            }
        }
    }
}

// ---------------------------------------------------------------------------
extern "C" void kernel_launch(void* const* d_in, const int* in_sizes, int n_in,
                              void* d_out, int out_size, void* d_ws, size_t ws_size,
                              hipStream_t stream)
{
    const float* query = (const float*)d_in[0];
    const float* key_  = (const float*)d_in[1];
    const float* value = (const float*)d_in[2];
    const int*   mask  = (const int*)d_in[3];
    const float* Wq    = (const float*)d_in[4];
    const float* bq    = (const float*)d_in[5];
    const float* Wk    = (const float*)d_in[6];
    const float* bk    = (const float*)d_in[7];
    const float* Wv    = (const float*)d_in[8];
    const float* bv    = (const float*)d_in[9];
    const float* Wo    = (const float*)d_in[10];
    const float* bo    = (const float*)d_in[11];
    float* out = (float*)d_out;

    unsigned short* cvt = (unsigned short*)d_ws;
    unsigned short* Aq  = cvt;
    unsigned short* Ak  = cvt + M4;
    unsigned short* Av  = cvt + 2 * M4;
    unsigned short* Wqb = cvt + 3 * M4;
    unsigned short* Wkb = Wqb + M1;
    unsigned short* Wvb = Wkb + M1;
    unsigned short* Wob = Wvb + M1;
    unsigned short* Qb  = Wob + M1;
    unsigned short* Kb  = Qb + M4;
    unsigned short* Vt  = Kb + M4;
    unsigned short* Ab  = Vt + M4;
    float*          mkf = (float*)(Ab + M4);

    CvtArgs ca;
    ca.src[0] = query; ca.src[1] = key_; ca.src[2] = value;
    ca.src[3] = Wq; ca.src[4] = Wk; ca.src[5] = Wv; ca.src[6] = Wo;
    ca.dst = cvt; ca.mask = mask; ca.maskf = mkf;
    cvt_bf16<<<dim3(16385), 256, 0, stream>>>(ca);

    GArgs ga;
    ga.A[0] = Aq;  ga.A[1] = Ak;  ga.A[2] = Av;
    ga.W[0] = Wqb; ga.W[1] = Wkb; ga.W[2] = Wvb;
    ga.bias[0] = bq; ga.bias[1] = bk; ga.bias[2] = bv;
    ga.C[0] = Qb; ga.C[1] = Kb; ga.C[2] = Vt;
    proj_gemm<<<dim3(768), 256, 0, stream>>>(ga);

    flash_attn<<<dim3(1024), 256, 0, stream>>>(Qb, Kb, Vt, mkf, Ab);
    out_gemm<<<dim3(512), 256, 0, stream>>>(Ab, Wob, bo, out);
}